// Round 15
// baseline (1525.572 us; speedup 1.0000x reference)
//
#include <hip/hip_runtime.h>

#define DEVI __device__ __forceinline__

constexpr int N_  = 8192;
constexpr int K_  = 15;
constexpr int E_  = N_ * K_;     // 122880
constexpr int FTS = 12;
constexpr float DT_ = 0.25f;

typedef __attribute__((ext_vector_type(8))) short short8x;
typedef __attribute__((ext_vector_type(4))) float float4x;

union U8 { unsigned int u[4]; short8x v; };

DEVI float sigf(float x) { return 1.0f / (1.0f + __expf(-x)); }
DEVI float tanhf_fast(float x) { float e = __expf(2.f * x); return 1.f - 2.f / (e + 1.f); }
DEVI unsigned int f2u(float x) { union { float f; unsigned int u; } c; c.f = x; return c.u; }
DEVI float u2f(unsigned int x) { union { unsigned int u; float f; } c; c.u = x; return c.f; }

DEVI void split8(const float* __restrict__ s, short8x& hi8, short8x& lo8) {
  U8 ph, pl;
#pragma unroll
  for (int p = 0; p < 4; p++) {
    float a0 = s[2*p], a1 = s[2*p+1];
    unsigned int u0 = f2u(a0), u1 = f2u(a1);
    unsigned int h0 = u0 & 0xFFFF0000u, h1 = u1 & 0xFFFF0000u;
    ph.u[p] = (u0 >> 16) | h1;
    float l0 = a0 - u2f(h0), l1 = a1 - u2f(h1);
    pl.u[p] = (f2u(l0) >> 16) | (f2u(l1) & 0xFFFF0000u);
  }
  hi8 = ph.v; lo8 = pl.v;
}

// ---------------------------------------------------------------- zero striped accumulators (13 accs x 16 slots x 16-float lines)
__global__ void k_zero(float* ss) {
  ss[blockIdx.x * 256 + threadIdx.x] = 0.f;
}

// ---------------------------------------------------------------- edge static
__global__ __launch_bounds__(256) void k_edge_static(
    const int* __restrict__ e1, const int* __restrict__ e2,
    const float* __restrict__ nsize, float* __restrict__ rad, float* __restrict__ szf)
{
  int e = blockIdx.x * 256 + threadIdx.x;
  if (e >= E_) return;
  int i1 = e1[e], i2 = e2[e];
  float s1x = nsize[i1*2+0], s1y = nsize[i1*2+1];
  float s2x = nsize[i2*2+0], s2y = nsize[i2*2+1];
  rad[e] = 0.5f * (sqrtf(s1x*s1x + s1y*s1y) + sqrtf(s2x*s2x + s2y*s2y));
  *(float4*)&szf[e*4] = make_float4(s1x, s1y, s2x, s2y);
}

// ---------------------------------------------------------------- hi-only bf16 B-fragments for edge W_e2
__global__ __launch_bounds__(256) void k_prep_hi(
    const float* __restrict__ W, unsigned short* __restrict__ out)
{
  int t = blockIdx.x * 256 + threadIdx.x;   // < 4096
  int fid = t >> 6, L = t & 63;
  int ks = fid >> 3, nt = fid & 7;
  int k0 = ks * 32 + (L >> 4) * 8;
  int n  = nt * 16 + (L & 15);
  unsigned int hi[4];
#pragma unroll
  for (int p = 0; p < 4; p++) {
    float w0 = W[(size_t)(k0 + 2*p) * 128 + n];
    float w1 = W[(size_t)(k0 + 2*p + 1) * 128 + n];
    hi[p] = (f2u(w0) >> 16) | (f2u(w1) & 0xFFFF0000u);
  }
  *(uint4*)(out + (size_t)fid * 512 + (size_t)L * 8) = make_uint4(hi[0], hi[1], hi[2], hi[3]);
}

// ---------------------------------------------------------------- generic hi-only bf16 B-fragment prep
__global__ __launch_bounds__(256) void k_prep1(
    const float* __restrict__ WA, const float* __restrict__ WB,
    int mode, int split, int wA, int wB, int Ktot, int NT, int nfrag,
    unsigned short* __restrict__ out)
{
  int t = blockIdx.x * 256 + threadIdx.x;
  int fid = t >> 6, L = t & 63;
  if (fid >= nfrag) return;
  int ks = fid / NT, nt = fid % NT;
  int k0 = ks * 32 + (L >> 4) * 8;
  int n  = nt * 16 + (L & 15);
  unsigned int hi[4];
#pragma unroll
  for (int p = 0; p < 4; p++) {
    float w0 = 0.f, w1 = 0.f;
    int ka = k0 + 2*p, kb = ka + 1;
    if (mode == 0) {
      if (ka < Ktot) w0 = (ka < split) ? WA[(size_t)ka*wA + n] : WB[(size_t)(ka-split)*wB + n];
      if (kb < Ktot) w1 = (kb < split) ? WA[(size_t)kb*wA + n] : WB[(size_t)(kb-split)*wB + n];
    } else {
      if (ka < Ktot) w0 = (n < split) ? WA[(size_t)ka*wA + n] : WB[(size_t)ka*wB + (n-split)];
      if (kb < Ktot) w1 = (n < split) ? WA[(size_t)kb*wA + n] : WB[(size_t)kb*wB + (n-split)];
    }
    hi[p] = (f2u(w0) >> 16) | (f2u(w1) & 0xFFFF0000u);
  }
  *(uint4*)(out + (size_t)fid * 512 + (size_t)L * 8) = make_uint4(hi[0], hi[1], hi[2], hi[3]);
}

// ---------------------------------------------------------------- xz GEMM (once), B hi-only, prefetch+dbuf staging
// gi output split: gi_ru (ir|iz packed bf16x2 per u32, byte-granular stores) + gi_n (f32)
__global__ __launch_bounds__(256) void k_xz_mfma(
    const float* __restrict__ hist, const float* __restrict__ z,
    const unsigned short* __restrict__ wB,
    const float* __restrict__ b_gh, const float* __restrict__ b_gih,
    float* __restrict__ gh0, unsigned int* __restrict__ gi_ru,
    float* __restrict__ gi_n)
{
  __shared__ __align__(16) float Abuf[2][64][36];
  const int tid = threadIdx.x;
  const int w = tid >> 6, lane = tid & 63;
  const int m = lane & 15, q = lane >> 4;
  const int n0 = blockIdx.x * 64;
  const int r_ = tid >> 2, c_ = (tid & 3) * 8;
  float4x acc[16];
#pragma unroll
  for (int tl = 0; tl < 16; tl++) acc[tl] = (float4x){0.f,0.f,0.f,0.f};

  auto LD = [&](int ks, float4& v0, float4& v1) {
    int kk = ks*32 + c_;
    int n = n0 + r_;
    if (kk < 256) {
      v0 = *(const float4*)&hist[(size_t)n*256 + kk];
      v1 = *(const float4*)&hist[(size_t)n*256 + kk + 4];
    } else if (kk == 256) {
      v0 = *(const float4*)&z[n*8];
      v1 = *(const float4*)&z[n*8 + 4];
    } else {
      v0 = make_float4(0,0,0,0); v1 = v0;
    }
  };
  {
    float4 v0, v1; LD(0, v0, v1);
    *(float4*)&Abuf[0][r_][c_]     = v0;
    *(float4*)&Abuf[0][r_][c_ + 4] = v1;
  }
  __syncthreads();
  for (int ks = 0; ks < 9; ks++) {
    float4 v0, v1;
    if (ks < 8) LD(ks + 1, v0, v1);
    short8x aHi, aLo;
    split8(&Abuf[ks & 1][w*16 + m][q*8], aHi, aLo);
#pragma unroll
    for (int tl = 0; tl < 16; tl++) {
      int nt = blockIdx.y*16 + tl;
      size_t off = (size_t)(ks*64 + nt) * 512 + (size_t)lane*8;
      short8x bh = *(const short8x*)(wB + off);
      acc[tl] = __builtin_amdgcn_mfma_f32_16x16x32_bf16(aLo, bh, acc[tl], 0, 0, 0);
      acc[tl] = __builtin_amdgcn_mfma_f32_16x16x32_bf16(aHi, bh, acc[tl], 0, 0, 0);
    }
    if (ks < 8) {
      *(float4*)&Abuf[(ks+1) & 1][r_][c_]     = v0;
      *(float4*)&Abuf[(ks+1) & 1][r_][c_ + 4] = v1;
      __syncthreads();
    }
  }
#pragma unroll
  for (int tl = 0; tl < 16; tl++) {
    int col = (blockIdx.y*16 + tl)*16 + m;
    float bias = (col < 256) ? b_gh[col] : b_gih[col - 256];
#pragma unroll
    for (int i = 0; i < 4; i++) {
      int n = n0 + w*16 + q*4 + i;
      float v = acc[tl][i] + bias;
      if (col < 256) {
        gh0[(size_t)n*256 + col] = v;
      } else {
        int cj = col - 256;
        int gate = cj >> 8, j = cj & 255;
        if (gate == 2) gi_n[(size_t)n*256 + j] = v;
        else ((unsigned short*)gi_ru)[((size_t)n*256 + j)*2 + gate] =
               (unsigned short)(f2u(v) >> 16);
      }
    }
  }
}

// ---------------------------------------------------------------- ALL 12 GRU steps in ONE kernel (v4: pre-split h).
__global__ __launch_bounds__(1024) void k_gru_all(
    const float* __restrict__ gh0, const unsigned short* __restrict__ wB,
    const float* __restrict__ b_ghh,
    const unsigned int* __restrict__ gi_ru, const float* __restrict__ gi_n,
    const float* __restrict__ W_proj, const float* __restrict__ b_proj,
    float* __restrict__ des)
{
  __shared__ __align__(16) unsigned short h_hi[32][264];
  __shared__ __align__(16) unsigned short h_lo[32][264];
  __shared__ float sm_des[8][32][2];
  const int tid = threadIdx.x;
  const int w = tid >> 6, lane = tid & 63;
  const int m = lane & 15, q = lane >> 4;
  const int rh = w & 1, jh = w >> 1;       // jh in [0,8)
  const int n0 = blockIdx.x * 32;

  {
    int r = tid >> 5, c = (tid & 31) * 8;
    float a8[8];
    const float4* src = (const float4*)&gh0[(size_t)(n0 + r)*256 + c];
    float4 v0 = src[0], v1 = src[1];
    a8[0]=v0.x; a8[1]=v0.y; a8[2]=v0.z; a8[3]=v0.w;
    a8[4]=v1.x; a8[5]=v1.y; a8[6]=v1.z; a8[7]=v1.w;
    short8x hi8, lo8;
    split8(a8, hi8, lo8);
    *(short8x*)&h_hi[r][c] = hi8;
    *(short8x*)&h_lo[r][c] = lo8;
  }
  float br_[2], bz_[2], bn_[2], wp0_[2], wp1_[2];
#pragma unroll
  for (int jt = 0; jt < 2; jt++) {
    int j = jh*32 + jt*16 + m;
    br_[jt] = b_ghh[j];
    bz_[jt] = b_ghh[256 + j];
    bn_[jt] = b_ghh[512 + j];
    wp0_[jt] = W_proj[j*2];
    wp1_[jt] = W_proj[j*2 + 1];
  }
  const float bp0 = b_proj[0], bp1 = b_proj[1];
  float ir_[2][4], iz_[2][4], inn_[2][4];
#pragma unroll
  for (int jt = 0; jt < 2; jt++) {
    int j = jh*32 + jt*16 + m;
#pragma unroll
    for (int i = 0; i < 4; i++) {
      int rl = rh*16 + q*4 + i;
      unsigned int ru = gi_ru[(size_t)(n0 + rl)*256 + j];
      ir_[jt][i]  = u2f(ru << 16);
      iz_[jt][i]  = u2f(ru & 0xFFFF0000u);
      inn_[jt][i] = gi_n[(size_t)(n0 + rl)*256 + j];
    }
  }
  const unsigned short* __restrict__ wLane = wB + (size_t)lane * 8;
  __syncthreads();

#pragma unroll 1
  for (int t = 0; t < FTS; t++) {
    float4x acc[6];
#pragma unroll
    for (int tl = 0; tl < 6; tl++) acc[tl] = (float4x){0.f,0.f,0.f,0.f};

#pragma unroll 2
    for (int ks = 0; ks < 8; ks++) {
      short8x aHi = *(const short8x*)&h_hi[rh*16 + m][ks*32 + q*8];
      short8x aLo = *(const short8x*)&h_lo[rh*16 + m][ks*32 + q*8];
#pragma unroll
      for (int tl = 0; tl < 6; tl++) {
        int g = tl >> 1, jt = tl & 1;
        int nt = g*16 + jh*2 + jt;
        short8x bh = *(const short8x*)(wLane + (size_t)(ks*48 + nt) * 512);
        acc[tl] = __builtin_amdgcn_mfma_f32_16x16x32_bf16(aLo, bh, acc[tl], 0, 0, 0);
        acc[tl] = __builtin_amdgcn_mfma_f32_16x16x32_bf16(aHi, bh, acc[tl], 0, 0, 0);
      }
    }
    __syncthreads();   // all waves done READING h for this step
    float pd0[4] = {0,0,0,0}, pd1[4] = {0,0,0,0};
#pragma unroll
    for (int jt = 0; jt < 2; jt++) {
      int j = jh*32 + jt*16 + m;
#pragma unroll
      for (int i = 0; i < 4; i++) {
        int rl = rh*16 + q*4 + i;
        float hold = u2f(((unsigned int)h_hi[rl][j]) << 16)
                   + u2f(((unsigned int)h_lo[rl][j]) << 16);
        float r = sigf(ir_[jt][i] + acc[0*2 + jt][i] + br_[jt]);
        float u = sigf(iz_[jt][i] + acc[1*2 + jt][i] + bz_[jt]);
        float nh = (1.f - u) * tanhf_fast(inn_[jt][i] + r * (acc[2*2 + jt][i] + bn_[jt])) + u * hold;
        unsigned int un = f2u(nh);
        unsigned int uh = un & 0xFFFF0000u;
        float lo = nh - u2f(uh);
        h_hi[rl][j] = (unsigned short)(un >> 16);   // exclusive per-thread cells
        h_lo[rl][j] = (unsigned short)(f2u(lo) >> 16);
        pd0[i] += nh * wp0_[jt];
        pd1[i] += nh * wp1_[jt];
      }
    }
#pragma unroll
    for (int off = 1; off < 16; off <<= 1) {
#pragma unroll
      for (int i = 0; i < 4; i++) {
        pd0[i] += __shfl_xor(pd0[i], off);
        pd1[i] += __shfl_xor(pd1[i], off);
      }
    }
    if (m == 0) {
#pragma unroll
      for (int i = 0; i < 4; i++) {
        sm_des[jh][rh*16 + q*4 + i][0] = pd0[i];
        sm_des[jh][rh*16 + q*4 + i][1] = pd1[i];
      }
    }
    __syncthreads();   // h + sm_des writes visible
    if (tid < 64) {
      int r = tid >> 1, c = tid & 1;
      float s = 0.f;
#pragma unroll
      for (int k8 = 0; k8 < 8; k8++) s += sm_des[k8][r][c];
      des[((size_t)t * N_ + n0 + r) * 2 + c] = s + (c ? bp1 : bp0);
    }
  }
}

// ---------------------------------------------------------------- FUSED LSTM + ACTION per step.
__global__ __launch_bounds__(512) void k_la(
    const float* __restrict__ ctxg, const float* __restrict__ h_in,
    const unsigned short* __restrict__ wBl,
    const float* __restrict__ b_ih, const float* __restrict__ b_hh,
    float* __restrict__ c_st, float* __restrict__ h_out,
    const float* __restrict__ z, const float* __restrict__ rel,
    const float* __restrict__ nwp, const float* __restrict__ nwp2,
    const unsigned short* __restrict__ wBa, const float* __restrict__ b_a1,
    const float* __restrict__ W_a2, const float* __restrict__ b_a2,
    float* __restrict__ prev, float* __restrict__ prev_st,
    float* __restrict__ outS, float* __restrict__ outU)
{
  __shared__ __align__(16) unsigned short A_hi[16][392];
  __shared__ __align__(16) unsigned short A_lo[16][392];
  __shared__ float sm_p[8][16][2];
  const int tid = threadIdx.x;
  const int lane = tid & 63;
  const int jh = tid >> 6;                 // wave 0..7
  const int m = lane & 15, q = lane >> 4;
  const int n0 = blockIdx.x * 16;

  // ---- stage A = [ctx(128) | h(256)] pre-split
  if (tid < 256) {                         // ctx: 16 rows x 128
    int r = tid >> 4, c = (tid & 15) * 8;
    float a8[8];
    const float4* src = (const float4*)&ctxg[(size_t)(n0 + r)*128 + c];
    float4 v0 = src[0], v1 = src[1];
    a8[0]=v0.x; a8[1]=v0.y; a8[2]=v0.z; a8[3]=v0.w;
    a8[4]=v1.x; a8[5]=v1.y; a8[6]=v1.z; a8[7]=v1.w;
    short8x hi8, lo8;
    split8(a8, hi8, lo8);
    *(short8x*)&A_hi[r][c] = hi8;
    *(short8x*)&A_lo[r][c] = lo8;
  }
  {                                        // h: 16 rows x 256
    int r = tid >> 5, c = (tid & 31) * 8;
    float a8[8];
    const float4* src = (const float4*)&h_in[(size_t)(n0 + r)*256 + c];
    float4 v0 = src[0], v1 = src[1];
    a8[0]=v0.x; a8[1]=v0.y; a8[2]=v0.z; a8[3]=v0.w;
    a8[4]=v1.x; a8[5]=v1.y; a8[6]=v1.z; a8[7]=v1.w;
    short8x hi8, lo8;
    split8(a8, hi8, lo8);
    *(short8x*)&A_hi[r][128 + c] = hi8;
    *(short8x*)&A_lo[r][128 + c] = lo8;
  }
  __syncthreads();

  // ---- LSTM phase: K=384 (12 ks), 8 acc frags (4 gates x 2 jt), j0 = jh*32
  const unsigned short* __restrict__ wLane = wBl + (size_t)lane * 8;
  float4x acc[8];
#pragma unroll
  for (int tl = 0; tl < 8; tl++) acc[tl] = (float4x){0.f,0.f,0.f,0.f};
#pragma unroll 2
  for (int ks = 0; ks < 12; ks++) {
    short8x aHi = *(const short8x*)&A_hi[m][ks*32 + q*8];
    short8x aLo = *(const short8x*)&A_lo[m][ks*32 + q*8];
#pragma unroll
    for (int tl = 0; tl < 8; tl++) {
      int g = tl >> 1, jt = tl & 1;
      int nt = g*16 + jh*2 + jt;
      short8x bh = *(const short8x*)(wLane + (size_t)(ks*64 + nt) * 512);
      acc[tl] = __builtin_amdgcn_mfma_f32_16x16x32_bf16(aLo, bh, acc[tl], 0, 0, 0);
      acc[tl] = __builtin_amdgcn_mfma_f32_16x16x32_bf16(aHi, bh, acc[tl], 0, 0, 0);
    }
  }
  __syncthreads();   // all waves done reading A before h overwrites it

  // ---- gates epilogue: write c_st + h_out (global), store h pre-split in LDS
#pragma unroll
  for (int jt = 0; jt < 2; jt++) {
    int j = jh*32 + jt*16 + m;
    float bi = b_ih[j]       + b_hh[j];
    float bf = b_ih[256 + j] + b_hh[256 + j];
    float bg = b_ih[512 + j] + b_hh[512 + j];
    float bo = b_ih[768 + j] + b_hh[768 + j];
#pragma unroll
    for (int i = 0; i < 4; i++) {
      int rl = q*4 + i;
      int n = n0 + rl;
      float g_i = sigf(acc[0*2 + jt][i] + bi);
      float g_f = sigf(acc[1*2 + jt][i] + bf);
      float g_g = tanhf_fast(acc[2*2 + jt][i] + bg);
      float g_o = sigf(acc[3*2 + jt][i] + bo);
      float cv = g_f * c_st[(size_t)n*256 + j] + g_i * g_g;
      c_st[(size_t)n*256 + j] = cv;
      float hv = g_o * tanhf_fast(cv);
      h_out[(size_t)n*256 + j] = hv;
      unsigned int uh = f2u(hv);
      unsigned int hh2 = uh & 0xFFFF0000u;
      float lo = hv - u2f(hh2);
      A_hi[rl][j] = (unsigned short)(uh >> 16);    // exclusive cells
      A_lo[rl][j] = (unsigned short)(f2u(lo) >> 16);
    }
  }
  __syncthreads();   // h visible to all waves

  // ---- ACTION phase: K=272 (9 ks: 8 from LDS h, 1 global tail), 2 frags
  float4x pacc[2];
  pacc[0] = (float4x){0.f,0.f,0.f,0.f};
  pacc[1] = (float4x){0.f,0.f,0.f,0.f};
  const unsigned short* __restrict__ waLane = wBa + (size_t)lane * 8;
#pragma unroll 2
  for (int ks = 0; ks < 9; ks++) {
    short8x aHi, aLo;
    if (ks < 8) {
      aHi = *(const short8x*)&A_hi[m][ks*32 + q*8];
      aLo = *(const short8x*)&A_lo[m][ks*32 + q*8];
    } else {
      float a8[8];
      int n = n0 + m;
      if (q == 0) {
        float4 v0 = *(const float4*)&z[n*8];
        float4 v1 = *(const float4*)&z[n*8 + 4];
        a8[0]=v0.x; a8[1]=v0.y; a8[2]=v0.z; a8[3]=v0.w;
        a8[4]=v1.x; a8[5]=v1.y; a8[6]=v1.z; a8[7]=v1.w;
      } else if (q == 1) {
        float4 rv = *(const float4*)&rel[n*4];
        float2 w1 = *(const float2*)&nwp[n*2];
        float2 w2 = *(const float2*)&nwp2[n*2];
        a8[0]=rv.x; a8[1]=rv.y; a8[2]=rv.z; a8[3]=rv.w;
        a8[4]=w1.x; a8[5]=w1.y; a8[6]=w2.x; a8[7]=w2.y;
      } else {
#pragma unroll
        for (int d = 0; d < 8; d++) a8[d] = 0.f;
      }
      split8(a8, aHi, aLo);
    }
#pragma unroll
    for (int jt = 0; jt < 2; jt++) {
      int ta = jh*2 + jt;
      short8x bh = *(const short8x*)(waLane + (size_t)(ks*16 + ta) * 512);
      pacc[jt] = __builtin_amdgcn_mfma_f32_16x16x32_bf16(aLo, bh, pacc[jt], 0, 0, 0);
      pacc[jt] = __builtin_amdgcn_mfma_f32_16x16x32_bf16(aHi, bh, pacc[jt], 0, 0, 0);
    }
  }
  float p0[4] = {0,0,0,0}, p1[4] = {0,0,0,0};
#pragma unroll
  for (int jt = 0; jt < 2; jt++) {
    int col = (jh*2 + jt)*16 + m;
    float ba = b_a1[col];
    float2 w2 = *(const float2*)&W_a2[col*2];
#pragma unroll
    for (int i = 0; i < 4; i++) {
      float hv = fmaxf(pacc[jt][i] + ba, 0.f);
      p0[i] += hv * w2.x;
      p1[i] += hv * w2.y;
    }
  }
#pragma unroll
  for (int off = 1; off < 16; off <<= 1) {
#pragma unroll
    for (int i = 0; i < 4; i++) {
      p0[i] += __shfl_xor(p0[i], off);
      p1[i] += __shfl_xor(p1[i], off);
    }
  }
  if (m == 0) {
#pragma unroll
    for (int i = 0; i < 4; i++) {
      sm_p[jh][q*4 + i][0] = p0[i];
      sm_p[jh][q*4 + i][1] = p1[i];
    }
  }
  __syncthreads();
  if (tid < 16) {
    int n = n0 + tid;
    float s0 = 0.f, s1 = 0.f;
#pragma unroll
    for (int k8 = 0; k8 < 8; k8++) { s0 += sm_p[k8][tid][0]; s1 += sm_p[k8][tid][1]; }
    const float hd = 0.5f * DT_ * DT_;
    float ux = tanhf_fast(s0 + b_a2[0]);
    float uy = tanhf_fast(s1 + b_a2[1]);
    float4 pv = *(const float4*)&prev[n*4];
    float4 ps = *(const float4*)&prev_st[n*4];
    float4 npv, nps;
    npv.x = pv.x + pv.z*DT_ + ux*hd;
    npv.y = pv.y + pv.w*DT_ + uy*hd;
    npv.z = pv.z + ux*DT_;
    npv.w = pv.w + uy*DT_;
    nps.x = ps.x + ps.z*DT_ + ux*hd;
    nps.y = ps.y + ps.w*DT_ + uy*hd;
    nps.z = ps.z + ux*DT_;
    nps.w = ps.w + uy*DT_;
    *(float4*)&prev[n*4] = npv;
    *(float4*)&prev_st[n*4] = nps;
    *(float4*)&outS[(size_t)n*4] = npv;
    outU[n*2]     = ux;
    outU[n*2 + 1] = uy;
  }
}

// ---------------------------------------------------------------- LSTM h0/c0 + prev copies
__global__ __launch_bounds__(256) void k_init_hc(
    const float* __restrict__ x_last, const float* __restrict__ x_st_last,
    const float* __restrict__ W_h0, const float* __restrict__ b_h0,
    const float* __restrict__ W_c0, const float* __restrict__ b_c0,
    float* __restrict__ h, float* __restrict__ c,
    float* __restrict__ prev, float* __restrict__ prev_st)
{
  const int n = blockIdx.x;
  const int j = threadIdx.x;
  float x0 = x_st_last[n*4], x1 = x_st_last[n*4+1], x2 = x_st_last[n*4+2], x3 = x_st_last[n*4+3];
  h[(size_t)n*256 + j] = b_h0[j] + x0*W_h0[j] + x1*W_h0[256+j] + x2*W_h0[512+j] + x3*W_h0[768+j];
  c[(size_t)n*256 + j] = b_c0[j] + x0*W_c0[j] + x1*W_c0[256+j] + x2*W_c0[512+j] + x3*W_c0[768+j];
  if (j < 4) prev[n*4 + j] = x_last[n*4 + j];
  else if (j < 8) prev_st[n*4 + (j-4)] = x_st_last[n*4 + (j-4)];
}

// ---------------------------------------------------------------- EDGE-ONLY kernel v3: 8 nodes/block, 512 threads, 1024 blocks.
// Mechanism (R8's TLP lesson applied to edge): waves/CU 16 -> 32 (2x latency
// hiding); one B-frag staging stream + barrier set now serves 8 waves instead
// of 4 (staging L2 traffic and barriers per node halve); grid 1024 = exactly
// 4 blocks/CU, whole dispatch co-resident. Per-wave code is UNCHANGED (wave g
// owns node n0+g's 16 edge-slots) -- only P0/staging indexing + LDS map differ.
// LDS (floats): stage 2x2048 @0 | feats[1024]@4096 | flags[128]@5120 |
//   relv[32]@5248 | watt2[64]@5280 | vatt[16]@5344 | red[8]@5360 -> 5368
// P3 transpose: 8 waves x 576 = 4608 floats, overlaps stage(4096)+feats[0:512]
// (both dead by then); flags/relv/etc live above 4608 -> safe.
__global__ __launch_bounds__(512) void k_edge(
    const float* __restrict__ prev, const float* __restrict__ prev_st,
    const float* __restrict__ x_st_last,
    const float* __restrict__ szf, const float* __restrict__ rad,
    const int* __restrict__ nobs, const int* __restrict__ e1, const int* __restrict__ e2,
    const float* __restrict__ W_e1, const float* __restrict__ b_e1,
    const unsigned short* __restrict__ wsB, const float* __restrict__ b_e2,
    const unsigned short* __restrict__ wattA, const float* __restrict__ W_att2,
    const float* __restrict__ v_att,
    const float* __restrict__ des_p, const float* __restrict__ des_t,
    const float* __restrict__ des_n,
    float* __restrict__ relg, float* __restrict__ nwp, float* __restrict__ nwp2,
    float* __restrict__ ctx, float* __restrict__ ss_t, float* __restrict__ cc)
{
  __shared__ __align__(16) float smem[5368];
  const int tid = threadIdx.x;
  const int eb = blockIdx.x;                 // 0..1023

  float* sm_stage = smem;
  float* sm_feats = smem + 4096;
  float* sm_flags = smem + 5120;
  float* sm_relv  = smem + 5248;
  float* sm_watt2 = smem + 5280;
  float* sm_vatt  = smem + 5344;
  float* sm_red   = smem + 5360;

  const int n0  = eb * 8;
  const int slot = (eb & 15) << 4;           // striped accumulator line
  const int lane = tid & 63;
  const int g    = tid >> 6;                 // wave 0..7 = node n0+g
  const int q = lane >> 4, m = lane & 15;

  // ---- P0
  if (tid >= 176 && tid < 192) sm_vatt[tid - 176] = v_att[tid - 176];
  if (tid >= 192 && tid < 256) sm_watt2[tid - 192] = W_att2[tid - 192];

  if (tid < 128) {
    float v = 0.f;
    if (tid < 120) {
      int gg = tid / 15, k = tid % 15;       // gg 0..7
      int idx = nobs[(n0 + gg) * 15 + k];
      float f[8] = {0,0,0,0,0,0,0,0};
      float fl = 0.f;
      if (idx > 0) {
        int e = idx - 1;
        int i1 = e1[e], i2 = e2[e];
#pragma unroll
        for (int d = 0; d < 4; d++) f[d] = prev[i2*4 + d] - prev[i1*4 + d];
        float4 sz = *(const float4*)&szf[(size_t)e*4];
        f[4] = sz.x; f[5] = sz.y; f[6] = sz.z; f[7] = sz.w;
        fl = 1.f;
        float dist = sqrtf(f[0]*f[0] + f[1]*f[1]);
        v = fmaxf(rad[e] - dist, 0.f);
      }
#pragma unroll
      for (int d = 0; d < 8; d++) sm_feats[(gg*16 + k)*8 + d] = f[d];
      sm_flags[gg*16 + k] = fl;
    } else {
      int gg = tid - 120;                    // 0..7: zero-fill k=15 slot
#pragma unroll
      for (int d = 0; d < 8; d++) sm_feats[(gg*16 + 15)*8 + d] = 0.f;
      sm_flags[gg*16 + 15] = 0.f;
    }
#pragma unroll
    for (int off = 32; off; off >>= 1) v += __shfl_down(v, off);
    if ((tid & 63) == 0) atomicAdd(cc + slot, v);   // lanes 0 of waves 0,1
  } else if (tid < 136) {
    int gg = tid - 128;                      // 0..7
    int n = n0 + gg;
    float4 ps = *(const float4*)&prev_st[n*4];
    float r0, r1, r2, r3;
    if (des_p) {
      float4 xs = *(const float4*)&x_st_last[n*4];
      r0 = ps.x - xs.x - des_p[n*2];
      r1 = ps.y - xs.y - des_p[n*2 + 1];
      r2 = ps.z - xs.z;
      r3 = ps.w - xs.w;
    } else { r0 = ps.x; r1 = ps.y; r2 = ps.z; r3 = ps.w; }
    sm_relv[gg*4+0] = r0; sm_relv[gg*4+1] = r1; sm_relv[gg*4+2] = r2; sm_relv[gg*4+3] = r3;
    *(float4*)&relg[n*4] = make_float4(r0, r1, r2, r3);
    nwp[n*2]      = des_t[n*2]     - ps.x;
    nwp[n*2 + 1]  = des_t[n*2 + 1] - ps.y;
    nwp2[n*2]     = des_n[n*2]     - ps.x;
    nwp2[n*2 + 1] = des_n[n*2 + 1] - ps.y;
    sm_red[gg] = r0*r0 + r1*r1;
  }
  // initial stage of ks=0 (hi-only, 8KB) into buf0: 512 threads x 1 uint4
  {
    const uint4* src = (const uint4*)wsB;
    uint4* dst = (uint4*)sm_stage;
    dst[tid] = src[tid];
  }
  __syncthreads();
  if (tid == 136) {
    float s = 0.f;
#pragma unroll
    for (int gg = 0; gg < 8; gg++) s += sm_red[gg];
    atomicAdd(ss_t + slot, s);
  }

  // ---- P1+P2 pipelined over ks (per-wave code identical to v2)
  float f[8];
  {
    const float4 fa = *(const float4*)&sm_feats[(g*16 + m)*8];
    const float4 fb = *(const float4*)&sm_feats[(g*16 + m)*8 + 4];
    f[0]=fa.x; f[1]=fa.y; f[2]=fa.z; f[3]=fa.w; f[4]=fb.x; f[5]=fb.y; f[6]=fb.z; f[7]=fb.w;
  }
  float4x encR[8];
#pragma unroll
  for (int nt = 0; nt < 8; nt++) encR[nt] = (float4x){0.f,0.f,0.f,0.f};
  const float4* We14 = (const float4*)W_e1;
  const float4* Be14 = (const float4*)b_e1;

  for (int ks = 0; ks < 8; ks++) {
    uint4 r0;
    if (ks < 7) {
      const uint4* src = (const uint4*)wsB + (ks + 1) * 512;
      r0 = src[tid];
    }
    short8x aHi, aLo;
    {
      float h8[8];
      float4 b0 = Be14[8*ks + 2*q];
      float4 b1 = Be14[8*ks + 2*q + 1];
      h8[0]=b0.x; h8[1]=b0.y; h8[2]=b0.z; h8[3]=b0.w; h8[4]=b1.x; h8[5]=b1.y; h8[6]=b1.z; h8[7]=b1.w;
#pragma unroll
      for (int d = 0; d < 8; d++) {
        float4 wa = We14[d*64 + ks*8 + 2*q];
        float4 wb = We14[d*64 + ks*8 + 2*q + 1];
        h8[0] += f[d]*wa.x; h8[1] += f[d]*wa.y; h8[2] += f[d]*wa.z; h8[3] += f[d]*wa.w;
        h8[4] += f[d]*wb.x; h8[5] += f[d]*wb.y; h8[6] += f[d]*wb.z; h8[7] += f[d]*wb.w;
      }
#pragma unroll
      for (int p = 0; p < 8; p++) h8[p] = fmaxf(h8[p], 0.f);
      split8(h8, aHi, aLo);
    }
    const unsigned short* sb = (const unsigned short*)sm_stage + (ks & 1) * 4096;
#pragma unroll
    for (int nt = 0; nt < 8; nt++) {
      short8x bh = *(const short8x*)(sb + nt*512 + lane*8);
      encR[nt] = __builtin_amdgcn_mfma_f32_16x16x32_bf16(aLo, bh, encR[nt], 0, 0, 0);
      encR[nt] = __builtin_amdgcn_mfma_f32_16x16x32_bf16(aHi, bh, encR[nt], 0, 0, 0);
    }
    if (ks < 7) {
      uint4* dst = (uint4*)sm_stage + ((ks + 1) & 1) * 512;
      dst[tid] = r0;
      __syncthreads();
    }
  }
  float4x fl4 = *(const float4x*)&sm_flags[g*16 + q*4];
#pragma unroll
  for (int nt = 0; nt < 8; nt++) {
    float b2 = b_e2[nt*16 + m];
#pragma unroll
    for (int i = 0; i < 4; i++) encR[nt][i] = (encR[nt][i] + b2) * fl4[i];
  }

  // ---- P3': scores = enc @ W_att1 via MFMA; per-wave 16x36 transpose region.
  // All waves must be done reading stage B-frags before tb overwrites:
  __syncthreads();
  float* tb = smem + g * 576;   // 8 waves x 576 = 4608 (stage + feats[0:512], both dead)
  float4x sacc = {0.f, 0.f, 0.f, 0.f};
#pragma unroll
  for (int ksc = 0; ksc < 4; ksc++) {
#pragma unroll
    for (int ntl = 0; ntl < 2; ntl++) {
#pragma unroll
      for (int i = 0; i < 4; i++)
        tb[(q*4 + i)*36 + ntl*16 + m] = encR[2*ksc + ntl][i];
    }
    __builtin_amdgcn_s_waitcnt(0);   // wave-synchronous: all 64 lanes' writes drained
    float a8[8];
    {
      const float4* tp = (const float4*)(tb + m*36 + q*8);
      float4 t0 = tp[0], t1 = tp[1];
      a8[0]=t0.x; a8[1]=t0.y; a8[2]=t0.z; a8[3]=t0.w;
      a8[4]=t1.x; a8[5]=t1.y; a8[6]=t1.z; a8[7]=t1.w;
    }
    __builtin_amdgcn_s_waitcnt(0);   // reads drained before next iter's writes
    short8x aH, aL;
    split8(a8, aH, aL);
    short8x bh = *(const short8x*)(wattA + ksc*512 + lane*8);
    sacc = __builtin_amdgcn_mfma_f32_16x16x32_bf16(aL, bh, sacc, 0, 0, 0);
    sacc = __builtin_amdgcn_mfma_f32_16x16x32_bf16(aH, bh, sacc, 0, 0, 0);
  }
  // sacc: lane (q,m) holds score[edge=q*4+i][a=m]

  // ---- P5: softmax + ctx
  float relw;
  {
    float4 rv = *(const float4*)&sm_relv[g*4];
    relw = rv.x * sm_watt2[m] + rv.y * sm_watt2[16 + m]
         + rv.z * sm_watt2[32 + m] + rv.w * sm_watt2[48 + m];
  }
  float vat = sm_vatt[m];
  float val[4];
#pragma unroll
  for (int i = 0; i < 4; i++) val[i] = tanhf_fast(sacc[i] + relw) * vat;
#pragma unroll
  for (int msk = 1; msk < 16; msk <<= 1) {
#pragma unroll
    for (int i = 0; i < 4; i++) val[i] += __shfl_xor(val[i], msk);
  }
  if (q == 3) val[3] = -3.0e38f;
  float mx = fmaxf(fmaxf(val[0], val[1]), fmaxf(val[2], val[3]));
  mx = fmaxf(mx, __shfl_xor(mx, 16));
  mx = fmaxf(mx, __shfl_xor(mx, 32));
  float4x ev;
  float ssum = 0.f;
#pragma unroll
  for (int i = 0; i < 4; i++) { ev[i] = __expf(val[i] - mx); ssum += ev[i]; }
  ssum += __shfl_xor(ssum, 16);
  ssum += __shfl_xor(ssum, 32);
  float inv = 1.f / ssum;
#pragma unroll
  for (int i = 0; i < 4; i++) ev[i] *= inv;

  float cpart[8];
#pragma unroll
  for (int nt = 0; nt < 8; nt++) {
    float cv = ev[0]*encR[nt][0] + ev[1]*encR[nt][1] + ev[2]*encR[nt][2] + ev[3]*encR[nt][3];
    cv += __shfl_xor(cv, 16);
    cv += __shfl_xor(cv, 32);
    cpart[nt] = cv;
  }
  float v0 = (q == 0) ? cpart[0] : (q == 1) ? cpart[2] : (q == 2) ? cpart[4] : cpart[6];
  float v1 = (q == 0) ? cpart[1] : (q == 1) ? cpart[3] : (q == 2) ? cpart[5] : cpart[7];
  size_t cb = (size_t)(n0 + g) * 128 + q*32 + m;
  ctx[cb]      = v0;
  ctx[cb + 16] = v1;
}

// ---------------------------------------------------------------- finalize scalars (reduce 16 striped slots per accumulator)
__global__ void k_final(const float* __restrict__ ss, float* __restrict__ out) {
  const int lane = threadIdx.x;   // 64 threads
  float red[13];
#pragma unroll
  for (int a = 0; a < 13; a++) {
    float v = (lane < 16) ? ss[a*256 + lane*16] : 0.f;
    v += __shfl_xor(v, 1);
    v += __shfl_xor(v, 2);
    v += __shfl_xor(v, 4);
    v += __shfl_xor(v, 8);
    red[a] = v;
  }
  if (lane == 0) {
    float t = 0.f;
    for (int i = 0; i < FTS; i++) t += sqrtf(red[i]);
    out[(size_t)FTS * N_ * 6]     = t / (float)N_;
    out[(size_t)FTS * N_ * 6 + 1] = red[12];
  }
}

// ================================================================ launch
extern "C" void kernel_launch(void* const* d_in, const int* in_sizes, int n_in,
                              void* d_out, int out_size, void* d_ws, size_t ws_size,
                              hipStream_t stream) {
  (void)in_sizes; (void)n_in; (void)out_size; (void)ws_size;
  const float* x_last    = (const float*)d_in[0];
  const float* x_st_last = (const float*)d_in[1];
  const float* hist_enc  = (const float*)d_in[2];
  const float* z         = (const float*)d_in[3];
  const float* node_size = (const float*)d_in[4];
  const float* W_h0 = (const float*)d_in[5];
  const float* b_h0 = (const float*)d_in[6];
  const float* W_c0 = (const float*)d_in[7];
  const float* b_c0 = (const float*)d_in[8];
  const float* W_gh = (const float*)d_in[9];
  const float* b_gh = (const float*)d_in[10];
  const float* W_gih = (const float*)d_in[11];
  const float* W_ghh = (const float*)d_in[12];
  const float* b_gih = (const float*)d_in[13];
  const float* b_ghh = (const float*)d_in[14];
  const float* W_proj = (const float*)d_in[15];
  const float* b_proj = (const float*)d_in[16];
  const float* W_att1 = (const float*)d_in[17];
  const float* W_att2 = (const float*)d_in[18];
  const float* v_att  = (const float*)d_in[19];
  const float* W_lih = (const float*)d_in[20];
  const float* W_lhh = (const float*)d_in[21];
  const float* b_lih = (const float*)d_in[22];
  const float* b_lhh = (const float*)d_in[23];
  const float* W_e1 = (const float*)d_in[24];
  const float* b_e1 = (const float*)d_in[25];
  const float* W_e2 = (const float*)d_in[26];
  const float* b_e2 = (const float*)d_in[27];
  const float* W_a1 = (const float*)d_in[28];
  const float* b_a1 = (const float*)d_in[29];
  const float* W_a2 = (const float*)d_in[30];
  const float* b_a2 = (const float*)d_in[31];
  const int* e1   = (const int*)d_in[32];
  const int* e2   = (const int*)d_in[33];
  const int* nobs = (const int*)d_in[34];
  float* out = (float*)d_out;

  // workspace carve (floats)
  float* wsf     = (float*)d_ws;
  float* prev    = wsf;
  float* prev_st = wsf + 32768;
  float* des     = wsf + 65536;             // 12*8192*2 = 196608 -> end 262144
  float* rad     = wsf + 262160;
  float* szf     = wsf + 385040;            // -> end 876560
  float* baseA   = wsf + 876560;            // union region, 5 units of N*256
  // serial-phase view (consumed by k_gru_all BEFORE the main loop starts)
  float* gh0           = baseA;                                   // unit 0
  unsigned int* gi_ru  = (unsigned int*)(baseA + (size_t)2 * N_ * 256);  // unit 2
  float* gi_n          = baseA + (size_t)3 * N_ * 256;            // unit 3
  // main phase view (reuses the same units after k_gru_all completes)
  float* hA   = baseA;
  float* hB   = baseA + (size_t)N_ * 256;
  float* cbuf = baseA + (size_t)2 * N_ * 256;
  float* ctx  = baseA + (size_t)3 * N_ * 256;
  float* rel  = baseA + (size_t)4 * N_ * 256;
  float* nwp  = rel + (size_t)N_ * 4;
  float* nwp2 = nwp + (size_t)N_ * 2;
  // prepped B fragments (hi-only)
  unsigned short* wsBe = (unsigned short*)(wsf + 11362320);
  unsigned short* wsBg = (unsigned short*)(wsf + 11427856);
  unsigned short* wsBl = (unsigned short*)(wsf + 11624464);
  unsigned short* wsBx = (unsigned short*)(wsf + 12017680);
  unsigned short* wsBa = (unsigned short*)(wsf + 12312592);
  unsigned short* wattA = (unsigned short*)(wsf + 12386320);  // 4 frags (2048 ush)
  // striped scalar accumulators: 13 accs x 16 slots x 16 floats = 3328 floats
  float* ssx = wsf + 12388368;

  k_zero<<<13, 256, 0, stream>>>(ssx);
  k_edge_static<<<(E_ + 255) / 256, 256, 0, stream>>>(e1, e2, node_size, rad, szf);

  k_prep_hi<<<16, 256, 0, stream>>>(W_e2, wsBe);
  k_prep1<<<96,  256, 0, stream>>>(W_ghh, W_ghh, 0, 256, 768,  768,  256, 48, 384, wsBg);
  k_prep1<<<192, 256, 0, stream>>>(W_lih, W_lhh, 0, 128, 1024, 1024, 384, 64, 768, wsBl);
  k_prep1<<<144, 256, 0, stream>>>(W_gh,  W_gih, 1, 256, 256,  768,  264, 64, 576, wsBx);
  k_prep1<<<36,  256, 0, stream>>>(W_a1,  W_a1,  0, 272, 256,  256,  272, 16, 144, wsBa);
  k_prep1<<<1,   256, 0, stream>>>(W_att1, W_att1, 0, 128, 16, 16, 128, 1, 4, wattA);

  // guide GRU: xz GEMM once, then ALL 12 steps in one resident kernel
  k_xz_mfma<<<dim3(128, 4), 256, 0, stream>>>(hist_enc, z, wsBx, b_gh, b_gih,
                                              gh0, gi_ru, gi_n);
  k_gru_all<<<256, 1024, 0, stream>>>(gh0, wsBg, b_ghh, gi_ru, gi_n,
                                      W_proj, b_proj, des);

  // main rollout: edge -> fused lstm+action, des fully precomputed
  k_init_hc<<<N_, 256, 0, stream>>>(x_last, x_st_last, W_h0, b_h0, W_c0, b_c0,
                                    hA, cbuf, prev, prev_st);
  float* hcur = hA;
  float* hnxt = hB;
  for (int t = 0; t < FTS; t++) {
    const float* des_t = des + (size_t)t * N_ * 2;
    const float* des_n = des + (size_t)((t + 1 < FTS) ? t + 1 : FTS - 1) * N_ * 2;
    const float* des_p = (t > 0) ? des + (size_t)(t - 1) * N_ * 2 : nullptr;
    k_edge<<<1024, 512, 0, stream>>>(prev, prev_st, x_st_last, szf, rad,
                                     nobs, e1, e2, W_e1, b_e1, wsBe, b_e2,
                                     wattA, W_att2, v_att,
                                     des_p, des_t, des_n,
                                     rel, nwp, nwp2, ctx,
                                     ssx + (size_t)t * 256, ssx + 12 * 256);
    k_la<<<512, 512, 0, stream>>>(ctx, hcur, wsBl, b_lih, b_lhh,
                                  cbuf, hnxt,
                                  z, rel, nwp, nwp2,
                                  wsBa, b_a1, W_a2, b_a2,
                                  prev, prev_st,
                                  out + (size_t)t * N_ * 4,
                                  out + (size_t)FTS * N_ * 4 + (size_t)t * N_ * 2);
    float* tmp = hcur; hcur = hnxt; hnxt = tmp;
  }
  k_final<<<1, 64, 0, stream>>>(ssx, out);
}

// Round 17
// 1290.267 us; speedup vs baseline: 1.1824x; 1.1824x over previous
//
#include <hip/hip_runtime.h>

#define DEVI __device__ __forceinline__

constexpr int N_  = 8192;
constexpr int K_  = 15;
constexpr int E_  = N_ * K_;     // 122880
constexpr int FTS = 12;
constexpr float DT_ = 0.25f;

typedef __attribute__((ext_vector_type(8))) short short8x;
typedef __attribute__((ext_vector_type(4))) float float4x;

union U8 { unsigned int u[4]; short8x v; };

DEVI float sigf(float x) { return 1.0f / (1.0f + __expf(-x)); }
DEVI float tanhf_fast(float x) { float e = __expf(2.f * x); return 1.f - 2.f / (e + 1.f); }
DEVI unsigned int f2u(float x) { union { float f; unsigned int u; } c; c.f = x; return c.u; }
DEVI float u2f(unsigned int x) { union { unsigned int u; float f; } c; c.u = x; return c.f; }

DEVI void split8(const float* __restrict__ s, short8x& hi8, short8x& lo8) {
  U8 ph, pl;
#pragma unroll
  for (int p = 0; p < 4; p++) {
    float a0 = s[2*p], a1 = s[2*p+1];
    unsigned int u0 = f2u(a0), u1 = f2u(a1);
    unsigned int h0 = u0 & 0xFFFF0000u, h1 = u1 & 0xFFFF0000u;
    ph.u[p] = (u0 >> 16) | h1;
    float l0 = a0 - u2f(h0), l1 = a1 - u2f(h1);
    pl.u[p] = (f2u(l0) >> 16) | (f2u(l1) & 0xFFFF0000u);
  }
  hi8 = ph.v; lo8 = pl.v;
}

// ---------------------------------------------------------------- zero striped accumulators (13 accs x 16 slots x 16-float lines)
__global__ void k_zero(float* ss) {
  ss[blockIdx.x * 256 + threadIdx.x] = 0.f;
}

// ---------------------------------------------------------------- edge static
__global__ __launch_bounds__(256) void k_edge_static(
    const int* __restrict__ e1, const int* __restrict__ e2,
    const float* __restrict__ nsize, float* __restrict__ rad, float* __restrict__ szf)
{
  int e = blockIdx.x * 256 + threadIdx.x;
  if (e >= E_) return;
  int i1 = e1[e], i2 = e2[e];
  float s1x = nsize[i1*2+0], s1y = nsize[i1*2+1];
  float s2x = nsize[i2*2+0], s2y = nsize[i2*2+1];
  rad[e] = 0.5f * (sqrtf(s1x*s1x + s1y*s1y) + sqrtf(s2x*s2x + s2y*s2y));
  *(float4*)&szf[e*4] = make_float4(s1x, s1y, s2x, s2y);
}

// ---------------------------------------------------------------- hi-only bf16 B-fragments for edge W_e2
__global__ __launch_bounds__(256) void k_prep_hi(
    const float* __restrict__ W, unsigned short* __restrict__ out)
{
  int t = blockIdx.x * 256 + threadIdx.x;   // < 4096
  int fid = t >> 6, L = t & 63;
  int ks = fid >> 3, nt = fid & 7;
  int k0 = ks * 32 + (L >> 4) * 8;
  int n  = nt * 16 + (L & 15);
  unsigned int hi[4];
#pragma unroll
  for (int p = 0; p < 4; p++) {
    float w0 = W[(size_t)(k0 + 2*p) * 128 + n];
    float w1 = W[(size_t)(k0 + 2*p + 1) * 128 + n];
    hi[p] = (f2u(w0) >> 16) | (f2u(w1) & 0xFFFF0000u);
  }
  *(uint4*)(out + (size_t)fid * 512 + (size_t)L * 8) = make_uint4(hi[0], hi[1], hi[2], hi[3]);
}

// ---------------------------------------------------------------- generic hi-only bf16 B-fragment prep
__global__ __launch_bounds__(256) void k_prep1(
    const float* __restrict__ WA, const float* __restrict__ WB,
    int mode, int split, int wA, int wB, int Ktot, int NT, int nfrag,
    unsigned short* __restrict__ out)
{
  int t = blockIdx.x * 256 + threadIdx.x;
  int fid = t >> 6, L = t & 63;
  if (fid >= nfrag) return;
  int ks = fid / NT, nt = fid % NT;
  int k0 = ks * 32 + (L >> 4) * 8;
  int n  = nt * 16 + (L & 15);
  unsigned int hi[4];
#pragma unroll
  for (int p = 0; p < 4; p++) {
    float w0 = 0.f, w1 = 0.f;
    int ka = k0 + 2*p, kb = ka + 1;
    if (mode == 0) {
      if (ka < Ktot) w0 = (ka < split) ? WA[(size_t)ka*wA + n] : WB[(size_t)(ka-split)*wB + n];
      if (kb < Ktot) w1 = (kb < split) ? WA[(size_t)kb*wA + n] : WB[(size_t)(kb-split)*wB + n];
    } else {
      if (ka < Ktot) w0 = (n < split) ? WA[(size_t)ka*wA + n] : WB[(size_t)ka*wB + (n-split)];
      if (kb < Ktot) w1 = (n < split) ? WA[(size_t)kb*wA + n] : WB[(size_t)kb*wB + (n-split)];
    }
    hi[p] = (f2u(w0) >> 16) | (f2u(w1) & 0xFFFF0000u);
  }
  *(uint4*)(out + (size_t)fid * 512 + (size_t)L * 8) = make_uint4(hi[0], hi[1], hi[2], hi[3]);
}

// ---------------------------------------------------------------- xz GEMM (once), B hi-only, prefetch+dbuf staging
// gi output split: gi_ru (ir|iz packed bf16x2 per u32, byte-granular stores) + gi_n (f32)
__global__ __launch_bounds__(256) void k_xz_mfma(
    const float* __restrict__ hist, const float* __restrict__ z,
    const unsigned short* __restrict__ wB,
    const float* __restrict__ b_gh, const float* __restrict__ b_gih,
    float* __restrict__ gh0, unsigned int* __restrict__ gi_ru,
    float* __restrict__ gi_n)
{
  __shared__ __align__(16) float Abuf[2][64][36];
  const int tid = threadIdx.x;
  const int w = tid >> 6, lane = tid & 63;
  const int m = lane & 15, q = lane >> 4;
  const int n0 = blockIdx.x * 64;
  const int r_ = tid >> 2, c_ = (tid & 3) * 8;
  float4x acc[16];
#pragma unroll
  for (int tl = 0; tl < 16; tl++) acc[tl] = (float4x){0.f,0.f,0.f,0.f};

  auto LD = [&](int ks, float4& v0, float4& v1) {
    int kk = ks*32 + c_;
    int n = n0 + r_;
    if (kk < 256) {
      v0 = *(const float4*)&hist[(size_t)n*256 + kk];
      v1 = *(const float4*)&hist[(size_t)n*256 + kk + 4];
    } else if (kk == 256) {
      v0 = *(const float4*)&z[n*8];
      v1 = *(const float4*)&z[n*8 + 4];
    } else {
      v0 = make_float4(0,0,0,0); v1 = v0;
    }
  };
  {
    float4 v0, v1; LD(0, v0, v1);
    *(float4*)&Abuf[0][r_][c_]     = v0;
    *(float4*)&Abuf[0][r_][c_ + 4] = v1;
  }
  __syncthreads();
  for (int ks = 0; ks < 9; ks++) {
    float4 v0, v1;
    if (ks < 8) LD(ks + 1, v0, v1);
    short8x aHi, aLo;
    split8(&Abuf[ks & 1][w*16 + m][q*8], aHi, aLo);
#pragma unroll
    for (int tl = 0; tl < 16; tl++) {
      int nt = blockIdx.y*16 + tl;
      size_t off = (size_t)(ks*64 + nt) * 512 + (size_t)lane*8;
      short8x bh = *(const short8x*)(wB + off);
      acc[tl] = __builtin_amdgcn_mfma_f32_16x16x32_bf16(aLo, bh, acc[tl], 0, 0, 0);
      acc[tl] = __builtin_amdgcn_mfma_f32_16x16x32_bf16(aHi, bh, acc[tl], 0, 0, 0);
    }
    if (ks < 8) {
      *(float4*)&Abuf[(ks+1) & 1][r_][c_]     = v0;
      *(float4*)&Abuf[(ks+1) & 1][r_][c_ + 4] = v1;
      __syncthreads();
    }
  }
#pragma unroll
  for (int tl = 0; tl < 16; tl++) {
    int col = (blockIdx.y*16 + tl)*16 + m;
    float bias = (col < 256) ? b_gh[col] : b_gih[col - 256];
#pragma unroll
    for (int i = 0; i < 4; i++) {
      int n = n0 + w*16 + q*4 + i;
      float v = acc[tl][i] + bias;
      if (col < 256) {
        gh0[(size_t)n*256 + col] = v;
      } else {
        int cj = col - 256;
        int gate = cj >> 8, j = cj & 255;
        if (gate == 2) gi_n[(size_t)n*256 + j] = v;
        else ((unsigned short*)gi_ru)[((size_t)n*256 + j)*2 + gate] =
               (unsigned short)(f2u(v) >> 16);
      }
    }
  }
}

// ---------------------------------------------------------------- ALL 12 GRU steps in ONE kernel (v4: pre-split h).
__global__ __launch_bounds__(1024) void k_gru_all(
    const float* __restrict__ gh0, const unsigned short* __restrict__ wB,
    const float* __restrict__ b_ghh,
    const unsigned int* __restrict__ gi_ru, const float* __restrict__ gi_n,
    const float* __restrict__ W_proj, const float* __restrict__ b_proj,
    float* __restrict__ des)
{
  __shared__ __align__(16) unsigned short h_hi[32][264];
  __shared__ __align__(16) unsigned short h_lo[32][264];
  __shared__ float sm_des[8][32][2];
  const int tid = threadIdx.x;
  const int w = tid >> 6, lane = tid & 63;
  const int m = lane & 15, q = lane >> 4;
  const int rh = w & 1, jh = w >> 1;       // jh in [0,8)
  const int n0 = blockIdx.x * 32;

  {
    int r = tid >> 5, c = (tid & 31) * 8;
    float a8[8];
    const float4* src = (const float4*)&gh0[(size_t)(n0 + r)*256 + c];
    float4 v0 = src[0], v1 = src[1];
    a8[0]=v0.x; a8[1]=v0.y; a8[2]=v0.z; a8[3]=v0.w;
    a8[4]=v1.x; a8[5]=v1.y; a8[6]=v1.z; a8[7]=v1.w;
    short8x hi8, lo8;
    split8(a8, hi8, lo8);
    *(short8x*)&h_hi[r][c] = hi8;
    *(short8x*)&h_lo[r][c] = lo8;
  }
  float br_[2], bz_[2], bn_[2], wp0_[2], wp1_[2];
#pragma unroll
  for (int jt = 0; jt < 2; jt++) {
    int j = jh*32 + jt*16 + m;
    br_[jt] = b_ghh[j];
    bz_[jt] = b_ghh[256 + j];
    bn_[jt] = b_ghh[512 + j];
    wp0_[jt] = W_proj[j*2];
    wp1_[jt] = W_proj[j*2 + 1];
  }
  const float bp0 = b_proj[0], bp1 = b_proj[1];
  float ir_[2][4], iz_[2][4], inn_[2][4];
#pragma unroll
  for (int jt = 0; jt < 2; jt++) {
    int j = jh*32 + jt*16 + m;
#pragma unroll
    for (int i = 0; i < 4; i++) {
      int rl = rh*16 + q*4 + i;
      unsigned int ru = gi_ru[(size_t)(n0 + rl)*256 + j];
      ir_[jt][i]  = u2f(ru << 16);
      iz_[jt][i]  = u2f(ru & 0xFFFF0000u);
      inn_[jt][i] = gi_n[(size_t)(n0 + rl)*256 + j];
    }
  }
  const unsigned short* __restrict__ wLane = wB + (size_t)lane * 8;
  __syncthreads();

#pragma unroll 1
  for (int t = 0; t < FTS; t++) {
    float4x acc[6];
#pragma unroll
    for (int tl = 0; tl < 6; tl++) acc[tl] = (float4x){0.f,0.f,0.f,0.f};

#pragma unroll 2
    for (int ks = 0; ks < 8; ks++) {
      short8x aHi = *(const short8x*)&h_hi[rh*16 + m][ks*32 + q*8];
      short8x aLo = *(const short8x*)&h_lo[rh*16 + m][ks*32 + q*8];
#pragma unroll
      for (int tl = 0; tl < 6; tl++) {
        int g = tl >> 1, jt = tl & 1;
        int nt = g*16 + jh*2 + jt;
        short8x bh = *(const short8x*)(wLane + (size_t)(ks*48 + nt) * 512);
        acc[tl] = __builtin_amdgcn_mfma_f32_16x16x32_bf16(aLo, bh, acc[tl], 0, 0, 0);
        acc[tl] = __builtin_amdgcn_mfma_f32_16x16x32_bf16(aHi, bh, acc[tl], 0, 0, 0);
      }
    }
    __syncthreads();   // all waves done READING h for this step
    float pd0[4] = {0,0,0,0}, pd1[4] = {0,0,0,0};
#pragma unroll
    for (int jt = 0; jt < 2; jt++) {
      int j = jh*32 + jt*16 + m;
#pragma unroll
      for (int i = 0; i < 4; i++) {
        int rl = rh*16 + q*4 + i;
        float hold = u2f(((unsigned int)h_hi[rl][j]) << 16)
                   + u2f(((unsigned int)h_lo[rl][j]) << 16);
        float r = sigf(ir_[jt][i] + acc[0*2 + jt][i] + br_[jt]);
        float u = sigf(iz_[jt][i] + acc[1*2 + jt][i] + bz_[jt]);
        float nh = (1.f - u) * tanhf_fast(inn_[jt][i] + r * (acc[2*2 + jt][i] + bn_[jt])) + u * hold;
        unsigned int un = f2u(nh);
        unsigned int uh = un & 0xFFFF0000u;
        float lo = nh - u2f(uh);
        h_hi[rl][j] = (unsigned short)(un >> 16);   // exclusive per-thread cells
        h_lo[rl][j] = (unsigned short)(f2u(lo) >> 16);
        pd0[i] += nh * wp0_[jt];
        pd1[i] += nh * wp1_[jt];
      }
    }
#pragma unroll
    for (int off = 1; off < 16; off <<= 1) {
#pragma unroll
      for (int i = 0; i < 4; i++) {
        pd0[i] += __shfl_xor(pd0[i], off);
        pd1[i] += __shfl_xor(pd1[i], off);
      }
    }
    if (m == 0) {
#pragma unroll
      for (int i = 0; i < 4; i++) {
        sm_des[jh][rh*16 + q*4 + i][0] = pd0[i];
        sm_des[jh][rh*16 + q*4 + i][1] = pd1[i];
      }
    }
    __syncthreads();   // h + sm_des writes visible
    if (tid < 64) {
      int r = tid >> 1, c = tid & 1;
      float s = 0.f;
#pragma unroll
      for (int k8 = 0; k8 < 8; k8++) s += sm_des[k8][r][c];
      des[((size_t)t * N_ + n0 + r) * 2 + c] = s + (c ? bp1 : bp0);
    }
  }
}

// ---------------------------------------------------------------- FUSED LSTM + ACTION per step.
__global__ __launch_bounds__(512) void k_la(
    const float* __restrict__ ctxg, const float* __restrict__ h_in,
    const unsigned short* __restrict__ wBl,
    const float* __restrict__ b_ih, const float* __restrict__ b_hh,
    float* __restrict__ c_st, float* __restrict__ h_out,
    const float* __restrict__ z, const float* __restrict__ rel,
    const float* __restrict__ nwp, const float* __restrict__ nwp2,
    const unsigned short* __restrict__ wBa, const float* __restrict__ b_a1,
    const float* __restrict__ W_a2, const float* __restrict__ b_a2,
    float* __restrict__ prev, float* __restrict__ prev_st,
    float* __restrict__ outS, float* __restrict__ outU)
{
  __shared__ __align__(16) unsigned short A_hi[16][392];
  __shared__ __align__(16) unsigned short A_lo[16][392];
  __shared__ float sm_p[8][16][2];
  const int tid = threadIdx.x;
  const int lane = tid & 63;
  const int jh = tid >> 6;                 // wave 0..7
  const int m = lane & 15, q = lane >> 4;
  const int n0 = blockIdx.x * 16;

  // ---- stage A = [ctx(128) | h(256)] pre-split
  if (tid < 256) {                         // ctx: 16 rows x 128
    int r = tid >> 4, c = (tid & 15) * 8;
    float a8[8];
    const float4* src = (const float4*)&ctxg[(size_t)(n0 + r)*128 + c];
    float4 v0 = src[0], v1 = src[1];
    a8[0]=v0.x; a8[1]=v0.y; a8[2]=v0.z; a8[3]=v0.w;
    a8[4]=v1.x; a8[5]=v1.y; a8[6]=v1.z; a8[7]=v1.w;
    short8x hi8, lo8;
    split8(a8, hi8, lo8);
    *(short8x*)&A_hi[r][c] = hi8;
    *(short8x*)&A_lo[r][c] = lo8;
  }
  {                                        // h: 16 rows x 256
    int r = tid >> 5, c = (tid & 31) * 8;
    float a8[8];
    const float4* src = (const float4*)&h_in[(size_t)(n0 + r)*256 + c];
    float4 v0 = src[0], v1 = src[1];
    a8[0]=v0.x; a8[1]=v0.y; a8[2]=v0.z; a8[3]=v0.w;
    a8[4]=v1.x; a8[5]=v1.y; a8[6]=v1.z; a8[7]=v1.w;
    short8x hi8, lo8;
    split8(a8, hi8, lo8);
    *(short8x*)&A_hi[r][128 + c] = hi8;
    *(short8x*)&A_lo[r][128 + c] = lo8;
  }
  __syncthreads();

  // ---- LSTM phase: K=384 (12 ks), 8 acc frags (4 gates x 2 jt), j0 = jh*32
  const unsigned short* __restrict__ wLane = wBl + (size_t)lane * 8;
  float4x acc[8];
#pragma unroll
  for (int tl = 0; tl < 8; tl++) acc[tl] = (float4x){0.f,0.f,0.f,0.f};
#pragma unroll 2
  for (int ks = 0; ks < 12; ks++) {
    short8x aHi = *(const short8x*)&A_hi[m][ks*32 + q*8];
    short8x aLo = *(const short8x*)&A_lo[m][ks*32 + q*8];
#pragma unroll
    for (int tl = 0; tl < 8; tl++) {
      int g = tl >> 1, jt = tl & 1;
      int nt = g*16 + jh*2 + jt;
      short8x bh = *(const short8x*)(wLane + (size_t)(ks*64 + nt) * 512);
      acc[tl] = __builtin_amdgcn_mfma_f32_16x16x32_bf16(aLo, bh, acc[tl], 0, 0, 0);
      acc[tl] = __builtin_amdgcn_mfma_f32_16x16x32_bf16(aHi, bh, acc[tl], 0, 0, 0);
    }
  }
  __syncthreads();   // all waves done reading A before h overwrites it

  // ---- gates epilogue: write c_st + h_out (global), store h pre-split in LDS
#pragma unroll
  for (int jt = 0; jt < 2; jt++) {
    int j = jh*32 + jt*16 + m;
    float bi = b_ih[j]       + b_hh[j];
    float bf = b_ih[256 + j] + b_hh[256 + j];
    float bg = b_ih[512 + j] + b_hh[512 + j];
    float bo = b_ih[768 + j] + b_hh[768 + j];
#pragma unroll
    for (int i = 0; i < 4; i++) {
      int rl = q*4 + i;
      int n = n0 + rl;
      float g_i = sigf(acc[0*2 + jt][i] + bi);
      float g_f = sigf(acc[1*2 + jt][i] + bf);
      float g_g = tanhf_fast(acc[2*2 + jt][i] + bg);
      float g_o = sigf(acc[3*2 + jt][i] + bo);
      float cv = g_f * c_st[(size_t)n*256 + j] + g_i * g_g;
      c_st[(size_t)n*256 + j] = cv;
      float hv = g_o * tanhf_fast(cv);
      h_out[(size_t)n*256 + j] = hv;
      unsigned int uh = f2u(hv);
      unsigned int hh2 = uh & 0xFFFF0000u;
      float lo = hv - u2f(hh2);
      A_hi[rl][j] = (unsigned short)(uh >> 16);    // exclusive cells
      A_lo[rl][j] = (unsigned short)(f2u(lo) >> 16);
    }
  }
  __syncthreads();   // h visible to all waves

  // ---- ACTION phase: K=272 (9 ks: 8 from LDS h, 1 global tail), 2 frags
  float4x pacc[2];
  pacc[0] = (float4x){0.f,0.f,0.f,0.f};
  pacc[1] = (float4x){0.f,0.f,0.f,0.f};
  const unsigned short* __restrict__ waLane = wBa + (size_t)lane * 8;
#pragma unroll 2
  for (int ks = 0; ks < 9; ks++) {
    short8x aHi, aLo;
    if (ks < 8) {
      aHi = *(const short8x*)&A_hi[m][ks*32 + q*8];
      aLo = *(const short8x*)&A_lo[m][ks*32 + q*8];
    } else {
      float a8[8];
      int n = n0 + m;
      if (q == 0) {
        float4 v0 = *(const float4*)&z[n*8];
        float4 v1 = *(const float4*)&z[n*8 + 4];
        a8[0]=v0.x; a8[1]=v0.y; a8[2]=v0.z; a8[3]=v0.w;
        a8[4]=v1.x; a8[5]=v1.y; a8[6]=v1.z; a8[7]=v1.w;
      } else if (q == 1) {
        float4 rv = *(const float4*)&rel[n*4];
        float2 w1 = *(const float2*)&nwp[n*2];
        float2 w2 = *(const float2*)&nwp2[n*2];
        a8[0]=rv.x; a8[1]=rv.y; a8[2]=rv.z; a8[3]=rv.w;
        a8[4]=w1.x; a8[5]=w1.y; a8[6]=w2.x; a8[7]=w2.y;
      } else {
#pragma unroll
        for (int d = 0; d < 8; d++) a8[d] = 0.f;
      }
      split8(a8, aHi, aLo);
    }
#pragma unroll
    for (int jt = 0; jt < 2; jt++) {
      int ta = jh*2 + jt;
      short8x bh = *(const short8x*)(waLane + (size_t)(ks*16 + ta) * 512);
      pacc[jt] = __builtin_amdgcn_mfma_f32_16x16x32_bf16(aLo, bh, pacc[jt], 0, 0, 0);
      pacc[jt] = __builtin_amdgcn_mfma_f32_16x16x32_bf16(aHi, bh, pacc[jt], 0, 0, 0);
    }
  }
  float p0[4] = {0,0,0,0}, p1[4] = {0,0,0,0};
#pragma unroll
  for (int jt = 0; jt < 2; jt++) {
    int col = (jh*2 + jt)*16 + m;
    float ba = b_a1[col];
    float2 w2 = *(const float2*)&W_a2[col*2];
#pragma unroll
    for (int i = 0; i < 4; i++) {
      float hv = fmaxf(pacc[jt][i] + ba, 0.f);
      p0[i] += hv * w2.x;
      p1[i] += hv * w2.y;
    }
  }
#pragma unroll
  for (int off = 1; off < 16; off <<= 1) {
#pragma unroll
    for (int i = 0; i < 4; i++) {
      p0[i] += __shfl_xor(p0[i], off);
      p1[i] += __shfl_xor(p1[i], off);
    }
  }
  if (m == 0) {
#pragma unroll
    for (int i = 0; i < 4; i++) {
      sm_p[jh][q*4 + i][0] = p0[i];
      sm_p[jh][q*4 + i][1] = p1[i];
    }
  }
  __syncthreads();
  if (tid < 16) {
    int n = n0 + tid;
    float s0 = 0.f, s1 = 0.f;
#pragma unroll
    for (int k8 = 0; k8 < 8; k8++) { s0 += sm_p[k8][tid][0]; s1 += sm_p[k8][tid][1]; }
    const float hd = 0.5f * DT_ * DT_;
    float ux = tanhf_fast(s0 + b_a2[0]);
    float uy = tanhf_fast(s1 + b_a2[1]);
    float4 pv = *(const float4*)&prev[n*4];
    float4 ps = *(const float4*)&prev_st[n*4];
    float4 npv, nps;
    npv.x = pv.x + pv.z*DT_ + ux*hd;
    npv.y = pv.y + pv.w*DT_ + uy*hd;
    npv.z = pv.z + ux*DT_;
    npv.w = pv.w + uy*DT_;
    nps.x = ps.x + ps.z*DT_ + ux*hd;
    nps.y = ps.y + ps.w*DT_ + uy*hd;
    nps.z = ps.z + ux*DT_;
    nps.w = ps.w + uy*DT_;
    *(float4*)&prev[n*4] = npv;
    *(float4*)&prev_st[n*4] = nps;
    *(float4*)&outS[(size_t)n*4] = npv;
    outU[n*2]     = ux;
    outU[n*2 + 1] = uy;
  }
}

// ---------------------------------------------------------------- LSTM h0/c0 + prev copies
__global__ __launch_bounds__(256) void k_init_hc(
    const float* __restrict__ x_last, const float* __restrict__ x_st_last,
    const float* __restrict__ W_h0, const float* __restrict__ b_h0,
    const float* __restrict__ W_c0, const float* __restrict__ b_c0,
    float* __restrict__ h, float* __restrict__ c,
    float* __restrict__ prev, float* __restrict__ prev_st)
{
  const int n = blockIdx.x;
  const int j = threadIdx.x;
  float x0 = x_st_last[n*4], x1 = x_st_last[n*4+1], x2 = x_st_last[n*4+2], x3 = x_st_last[n*4+3];
  h[(size_t)n*256 + j] = b_h0[j] + x0*W_h0[j] + x1*W_h0[256+j] + x2*W_h0[512+j] + x3*W_h0[768+j];
  c[(size_t)n*256 + j] = b_c0[j] + x0*W_c0[j] + x1*W_c0[256+j] + x2*W_c0[512+j] + x3*W_c0[768+j];
  if (j < 4) prev[n*4 + j] = x_last[n*4 + j];
  else if (j < 8) prev_st[n*4 + (j-4)] = x_st_last[n*4 + (j-4)];
}

// ---------------------------------------------------------------- EDGE-ONLY kernel (2048 blocks, 4 nodes each)
// (256,4): verified best. Ledger of failed alternatives: direct-L2 B-frags
// (R9, 4x L2 traffic), launch_bounds (256,8) (R13, allocator squeeze -> spill),
// 8-node/512-thread blocks (R15, halved staging ILP + wider barriers).
__global__ __launch_bounds__(256, 4) void k_edge(
    const float* __restrict__ prev, const float* __restrict__ prev_st,
    const float* __restrict__ x_st_last,
    const float* __restrict__ szf, const float* __restrict__ rad,
    const int* __restrict__ nobs, const int* __restrict__ e1, const int* __restrict__ e2,
    const float* __restrict__ W_e1, const float* __restrict__ b_e1,
    const unsigned short* __restrict__ wsB, const float* __restrict__ b_e2,
    const unsigned short* __restrict__ wattA, const float* __restrict__ W_att2,
    const float* __restrict__ v_att,
    const float* __restrict__ des_p, const float* __restrict__ des_t,
    const float* __restrict__ des_n,
    float* __restrict__ relg, float* __restrict__ nwp, float* __restrict__ nwp2,
    float* __restrict__ ctx, float* __restrict__ ss_t, float* __restrict__ cc)
{
  __shared__ __align__(16) float smem[4776];
  const int tid = threadIdx.x;
  const int eb = blockIdx.x;                 // edge id 0..2047

  float* sm_stage = smem;
  float* sm_feats = smem + 4096;
  float* sm_flags = smem + 4608;
  float* sm_relv  = smem + 4672;
  float* sm_watt2 = smem + 4688;
  float* sm_vatt  = smem + 4752;
  float* sm_red   = smem + 4768;

  const int n0  = eb * 4;
  const int slot = (eb & 15) << 4;           // striped accumulator line
  const int lane = tid & 63;
  const int g    = tid >> 6;
  const int q = lane >> 4, m = lane & 15;

  // ---- P0
  if (tid >= 176 && tid < 192) sm_vatt[tid - 176] = v_att[tid - 176];
  if (tid >= 192) sm_watt2[tid - 192] = W_att2[tid - 192];

  if (tid < 64) {
    float v = 0.f;
    if (tid < 60) {
      int gg = tid / 15, k = tid % 15;
      int idx = nobs[(n0 + gg) * 15 + k];
      float f[8] = {0,0,0,0,0,0,0,0};
      float fl = 0.f;
      if (idx > 0) {
        int e = idx - 1;
        int i1 = e1[e], i2 = e2[e];
#pragma unroll
        for (int d = 0; d < 4; d++) f[d] = prev[i2*4 + d] - prev[i1*4 + d];
        float4 sz = *(const float4*)&szf[(size_t)e*4];
        f[4] = sz.x; f[5] = sz.y; f[6] = sz.z; f[7] = sz.w;
        fl = 1.f;
        float dist = sqrtf(f[0]*f[0] + f[1]*f[1]);
        v = fmaxf(rad[e] - dist, 0.f);
      }
#pragma unroll
      for (int d = 0; d < 8; d++) sm_feats[(gg*16 + k)*8 + d] = f[d];
      sm_flags[gg*16 + k] = fl;
    } else {
      int gg = tid - 60;
#pragma unroll
      for (int d = 0; d < 8; d++) sm_feats[(gg*16 + 15)*8 + d] = 0.f;
      sm_flags[gg*16 + 15] = 0.f;
    }
#pragma unroll
    for (int off = 32; off; off >>= 1) v += __shfl_down(v, off);
    if (tid == 0) atomicAdd(cc + slot, v);
  } else if (tid < 68) {
    int gg = tid - 64;
    int n = n0 + gg;
    float4 ps = *(const float4*)&prev_st[n*4];
    float r0, r1, r2, r3;
    if (des_p) {
      float4 xs = *(const float4*)&x_st_last[n*4];
      r0 = ps.x - xs.x - des_p[n*2];
      r1 = ps.y - xs.y - des_p[n*2 + 1];
      r2 = ps.z - xs.z;
      r3 = ps.w - xs.w;
    } else { r0 = ps.x; r1 = ps.y; r2 = ps.z; r3 = ps.w; }
    sm_relv[gg*4+0] = r0; sm_relv[gg*4+1] = r1; sm_relv[gg*4+2] = r2; sm_relv[gg*4+3] = r3;
    *(float4*)&relg[n*4] = make_float4(r0, r1, r2, r3);
    nwp[n*2]      = des_t[n*2]     - ps.x;
    nwp[n*2 + 1]  = des_t[n*2 + 1] - ps.y;
    nwp2[n*2]     = des_n[n*2]     - ps.x;
    nwp2[n*2 + 1] = des_n[n*2 + 1] - ps.y;
    sm_red[gg] = r0*r0 + r1*r1;
  }
  // initial stage of ks=0 (hi-only, 8KB) into buf0
  {
    const uint4* src = (const uint4*)wsB;
    uint4* dst = (uint4*)sm_stage;
    dst[tid]       = src[tid];
    dst[tid + 256] = src[tid + 256];
  }
  __syncthreads();
  if (tid == 64) atomicAdd(ss_t + slot, sm_red[0] + sm_red[1] + sm_red[2] + sm_red[3]);

  // ---- P1+P2 pipelined over ks
  float f[8];
  {
    const float4 fa = *(const float4*)&sm_feats[(g*16 + m)*8];
    const float4 fb = *(const float4*)&sm_feats[(g*16 + m)*8 + 4];
    f[0]=fa.x; f[1]=fa.y; f[2]=fa.z; f[3]=fa.w; f[4]=fb.x; f[5]=fb.y; f[6]=fb.z; f[7]=fb.w;
  }
  float4x encR[8];
#pragma unroll
  for (int nt = 0; nt < 8; nt++) encR[nt] = (float4x){0.f,0.f,0.f,0.f};
  const float4* We14 = (const float4*)W_e1;
  const float4* Be14 = (const float4*)b_e1;

  for (int ks = 0; ks < 8; ks++) {
    uint4 r0, r1;
    if (ks < 7) {
      const uint4* src = (const uint4*)wsB + (ks + 1) * 512;
      r0 = src[tid];
      r1 = src[tid + 256];
    }
    short8x aHi, aLo;
    {
      float h8[8];
      float4 b0 = Be14[8*ks + 2*q];
      float4 b1 = Be14[8*ks + 2*q + 1];
      h8[0]=b0.x; h8[1]=b0.y; h8[2]=b0.z; h8[3]=b0.w; h8[4]=b1.x; h8[5]=b1.y; h8[6]=b1.z; h8[7]=b1.w;
#pragma unroll
      for (int d = 0; d < 8; d++) {
        float4 wa = We14[d*64 + ks*8 + 2*q];
        float4 wb = We14[d*64 + ks*8 + 2*q + 1];
        h8[0] += f[d]*wa.x; h8[1] += f[d]*wa.y; h8[2] += f[d]*wa.z; h8[3] += f[d]*wa.w;
        h8[4] += f[d]*wb.x; h8[5] += f[d]*wb.y; h8[6] += f[d]*wb.z; h8[7] += f[d]*wb.w;
      }
#pragma unroll
      for (int p = 0; p < 8; p++) h8[p] = fmaxf(h8[p], 0.f);
      split8(h8, aHi, aLo);
    }
    const unsigned short* sb = (const unsigned short*)sm_stage + (ks & 1) * 4096;
#pragma unroll
    for (int nt = 0; nt < 8; nt++) {
      short8x bh = *(const short8x*)(sb + nt*512 + lane*8);
      encR[nt] = __builtin_amdgcn_mfma_f32_16x16x32_bf16(aLo, bh, encR[nt], 0, 0, 0);
      encR[nt] = __builtin_amdgcn_mfma_f32_16x16x32_bf16(aHi, bh, encR[nt], 0, 0, 0);
    }
    if (ks < 7) {
      uint4* dst = (uint4*)sm_stage + ((ks + 1) & 1) * 512;
      dst[tid]       = r0;
      dst[tid + 256] = r1;
      __syncthreads();
    }
  }
  float4x fl4 = *(const float4x*)&sm_flags[g*16 + q*4];
#pragma unroll
  for (int nt = 0; nt < 8; nt++) {
    float b2 = b_e2[nt*16 + m];
#pragma unroll
    for (int i = 0; i < 4; i++) encR[nt][i] = (encR[nt][i] + b2) * fl4[i];
  }

  // ---- P3': scores = enc @ W_att1 via MFMA; per-wave 16x36 LDS transpose region.
  __syncthreads();
  {
  }
  float* tb = sm_stage + g * 576;   // 16 rows x 36 (4 waves -> 2304 <= 4096)
  float4x sacc = {0.f, 0.f, 0.f, 0.f};
#pragma unroll
  for (int ksc = 0; ksc < 4; ksc++) {
#pragma unroll
    for (int ntl = 0; ntl < 2; ntl++) {
#pragma unroll
      for (int i = 0; i < 4; i++)
        tb[(q*4 + i)*36 + ntl*16 + m] = encR[2*ksc + ntl][i];
    }
    __builtin_amdgcn_s_waitcnt(0);   // wave-synchronous: all 64 lanes' writes drained
    float a8[8];
    {
      const float4* tp = (const float4*)(tb + m*36 + q*8);
      float4 t0 = tp[0], t1 = tp[1];
      a8[0]=t0.x; a8[1]=t0.y; a8[2]=t0.z; a8[3]=t0.w;
      a8[4]=t1.x; a8[5]=t1.y; a8[6]=t1.z; a8[7]=t1.w;
    }
    __builtin_amdgcn_s_waitcnt(0);   // reads drained before next iter's writes
    short8x aH, aL;
    split8(a8, aH, aL);
    short8x bh = *(const short8x*)(wattA + ksc*512 + lane*8);
    sacc = __builtin_amdgcn_mfma_f32_16x16x32_bf16(aL, bh, sacc, 0, 0, 0);
    sacc = __builtin_amdgcn_mfma_f32_16x16x32_bf16(aH, bh, sacc, 0, 0, 0);
  }
  // sacc: lane (q,m) holds score[edge=q*4+i][a=m]

  // ---- P5: softmax + ctx
  float relw;
  {
    float4 rv = *(const float4*)&sm_relv[g*4];
    relw = rv.x * sm_watt2[m] + rv.y * sm_watt2[16 + m]
         + rv.z * sm_watt2[32 + m] + rv.w * sm_watt2[48 + m];
  }
  float vat = sm_vatt[m];
  float val[4];
#pragma unroll
  for (int i = 0; i < 4; i++) val[i] = tanhf_fast(sacc[i] + relw) * vat;
#pragma unroll
  for (int msk = 1; msk < 16; msk <<= 1) {
#pragma unroll
    for (int i = 0; i < 4; i++) val[i] += __shfl_xor(val[i], msk);
  }
  if (q == 3) val[3] = -3.0e38f;
  float mx = fmaxf(fmaxf(val[0], val[1]), fmaxf(val[2], val[3]));
  mx = fmaxf(mx, __shfl_xor(mx, 16));
  mx = fmaxf(mx, __shfl_xor(mx, 32));
  float4x ev;
  float ssum = 0.f;
#pragma unroll
  for (int i = 0; i < 4; i++) { ev[i] = __expf(val[i] - mx); ssum += ev[i]; }
  ssum += __shfl_xor(ssum, 16);
  ssum += __shfl_xor(ssum, 32);
  float inv = 1.f / ssum;
#pragma unroll
  for (int i = 0; i < 4; i++) ev[i] *= inv;

  float cpart[8];
#pragma unroll
  for (int nt = 0; nt < 8; nt++) {
    float cv = ev[0]*encR[nt][0] + ev[1]*encR[nt][1] + ev[2]*encR[nt][2] + ev[3]*encR[nt][3];
    cv += __shfl_xor(cv, 16);
    cv += __shfl_xor(cv, 32);
    cpart[nt] = cv;
  }
  float v0 = (q == 0) ? cpart[0] : (q == 1) ? cpart[2] : (q == 2) ? cpart[4] : cpart[6];
  float v1 = (q == 0) ? cpart[1] : (q == 1) ? cpart[3] : (q == 2) ? cpart[5] : cpart[7];
  size_t cb = (size_t)(n0 + g) * 128 + q*32 + m;
  ctx[cb]      = v0;
  ctx[cb + 16] = v1;
}

// ---------------------------------------------------------------- finalize scalars (reduce 16 striped slots per accumulator)
__global__ void k_final(const float* __restrict__ ss, float* __restrict__ out) {
  const int lane = threadIdx.x;   // 64 threads
  float red[13];
#pragma unroll
  for (int a = 0; a < 13; a++) {
    float v = (lane < 16) ? ss[a*256 + lane*16] : 0.f;
    v += __shfl_xor(v, 1);
    v += __shfl_xor(v, 2);
    v += __shfl_xor(v, 4);
    v += __shfl_xor(v, 8);
    red[a] = v;
  }
  if (lane == 0) {
    float t = 0.f;
    for (int i = 0; i < FTS; i++) t += sqrtf(red[i]);
    out[(size_t)FTS * N_ * 6]     = t / (float)N_;
    out[(size_t)FTS * N_ * 6 + 1] = red[12];
  }
}

// ================================================================ launch
extern "C" void kernel_launch(void* const* d_in, const int* in_sizes, int n_in,
                              void* d_out, int out_size, void* d_ws, size_t ws_size,
                              hipStream_t stream) {
  (void)in_sizes; (void)n_in; (void)out_size; (void)ws_size;
  const float* x_last    = (const float*)d_in[0];
  const float* x_st_last = (const float*)d_in[1];
  const float* hist_enc  = (const float*)d_in[2];
  const float* z         = (const float*)d_in[3];
  const float* node_size = (const float*)d_in[4];
  const float* W_h0 = (const float*)d_in[5];
  const float* b_h0 = (const float*)d_in[6];
  const float* W_c0 = (const float*)d_in[7];
  const float* b_c0 = (const float*)d_in[8];
  const float* W_gh = (const float*)d_in[9];
  const float* b_gh = (const float*)d_in[10];
  const float* W_gih = (const float*)d_in[11];
  const float* W_ghh = (const float*)d_in[12];
  const float* b_gih = (const float*)d_in[13];
  const float* b_ghh = (const float*)d_in[14];
  const float* W_proj = (const float*)d_in[15];
  const float* b_proj = (const float*)d_in[16];
  const float* W_att1 = (const float*)d_in[17];
  const float* W_att2 = (const float*)d_in[18];
  const float* v_att  = (const float*)d_in[19];
  const float* W_lih = (const float*)d_in[20];
  const float* W_lhh = (const float*)d_in[21];
  const float* b_lih = (const float*)d_in[22];
  const float* b_lhh = (const float*)d_in[23];
  const float* W_e1 = (const float*)d_in[24];
  const float* b_e1 = (const float*)d_in[25];
  const float* W_e2 = (const float*)d_in[26];
  const float* b_e2 = (const float*)d_in[27];
  const float* W_a1 = (const float*)d_in[28];
  const float* b_a1 = (const float*)d_in[29];
  const float* W_a2 = (const float*)d_in[30];
  const float* b_a2 = (const float*)d_in[31];
  const int* e1   = (const int*)d_in[32];
  const int* e2   = (const int*)d_in[33];
  const int* nobs = (const int*)d_in[34];
  float* out = (float*)d_out;

  // workspace carve (floats)
  float* wsf     = (float*)d_ws;
  float* prev    = wsf;
  float* prev_st = wsf + 32768;
  float* des     = wsf + 65536;             // 12*8192*2 = 196608 -> end 262144
  float* rad     = wsf + 262160;
  float* szf     = wsf + 385040;            // -> end 876560
  float* baseA   = wsf + 876560;            // union region, 5 units of N*256
  // serial-phase view (consumed by k_gru_all BEFORE the main loop starts)
  float* gh0           = baseA;                                   // unit 0
  unsigned int* gi_ru  = (unsigned int*)(baseA + (size_t)2 * N_ * 256);  // unit 2
  float* gi_n          = baseA + (size_t)3 * N_ * 256;            // unit 3
  // main phase view (reuses the same units after k_gru_all completes)
  float* hA   = baseA;
  float* hB   = baseA + (size_t)N_ * 256;
  float* cbuf = baseA + (size_t)2 * N_ * 256;
  float* ctx  = baseA + (size_t)3 * N_ * 256;
  float* rel  = baseA + (size_t)4 * N_ * 256;
  float* nwp  = rel + (size_t)N_ * 4;
  float* nwp2 = nwp + (size_t)N_ * 2;
  // prepped B fragments (hi-only)
  unsigned short* wsBe = (unsigned short*)(wsf + 11362320);
  unsigned short* wsBg = (unsigned short*)(wsf + 11427856);
  unsigned short* wsBl = (unsigned short*)(wsf + 11624464);
  unsigned short* wsBx = (unsigned short*)(wsf + 12017680);
  unsigned short* wsBa = (unsigned short*)(wsf + 12312592);
  unsigned short* wattA = (unsigned short*)(wsf + 12386320);  // 4 frags (2048 ush)
  // striped scalar accumulators: 13 accs x 16 slots x 16 floats = 3328 floats
  float* ssx = wsf + 12388368;

  k_zero<<<13, 256, 0, stream>>>(ssx);
  k_edge_static<<<(E_ + 255) / 256, 256, 0, stream>>>(e1, e2, node_size, rad, szf);

  k_prep_hi<<<16, 256, 0, stream>>>(W_e2, wsBe);
  k_prep1<<<96,  256, 0, stream>>>(W_ghh, W_ghh, 0, 256, 768,  768,  256, 48, 384, wsBg);
  k_prep1<<<192, 256, 0, stream>>>(W_lih, W_lhh, 0, 128, 1024, 1024, 384, 64, 768, wsBl);
  k_prep1<<<144, 256, 0, stream>>>(W_gh,  W_gih, 1, 256, 256,  768,  264, 64, 576, wsBx);
  k_prep1<<<36,  256, 0, stream>>>(W_a1,  W_a1,  0, 272, 256,  256,  272, 16, 144, wsBa);
  k_prep1<<<1,   256, 0, stream>>>(W_att1, W_att1, 0, 128, 16, 16, 128, 1, 4, wattA);

  // guide GRU: xz GEMM once, then ALL 12 steps in one resident kernel
  k_xz_mfma<<<dim3(128, 4), 256, 0, stream>>>(hist_enc, z, wsBx, b_gh, b_gih,
                                              gh0, gi_ru, gi_n);
  k_gru_all<<<256, 1024, 0, stream>>>(gh0, wsBg, b_ghh, gi_ru, gi_n,
                                      W_proj, b_proj, des);

  // main rollout: edge -> fused lstm+action, des fully precomputed
  k_init_hc<<<N_, 256, 0, stream>>>(x_last, x_st_last, W_h0, b_h0, W_c0, b_c0,
                                    hA, cbuf, prev, prev_st);
  float* hcur = hA;
  float* hnxt = hB;
  for (int t = 0; t < FTS; t++) {
    const float* des_t = des + (size_t)t * N_ * 2;
    const float* des_n = des + (size_t)((t + 1 < FTS) ? t + 1 : FTS - 1) * N_ * 2;
    const float* des_p = (t > 0) ? des + (size_t)(t - 1) * N_ * 2 : nullptr;
    k_edge<<<2048, 256, 0, stream>>>(prev, prev_st, x_st_last, szf, rad,
                                     nobs, e1, e2, W_e1, b_e1, wsBe, b_e2,
                                     wattA, W_att2, v_att,
                                     des_p, des_t, des_n,
                                     rel, nwp, nwp2, ctx,
                                     ssx + (size_t)t * 256, ssx + 12 * 256);
    k_la<<<512, 512, 0, stream>>>(ctx, hcur, wsBl, b_lih, b_lhh,
                                  cbuf, hnxt,
                                  z, rel, nwp, nwp2,
                                  wsBa, b_a1, W_a2, b_a2,
                                  prev, prev_st,
                                  out + (size_t)t * N_ * 4,
                                  out + (size_t)FTS * N_ * 4 + (size_t)t * N_ * 2);
    float* tmp = hcur; hcur = hnxt; hnxt = tmp;
  }
  k_final<<<1, 64, 0, stream>>>(ssx, out);
}